// Round 9
// baseline (1064.767 us; speedup 1.0000x reference)
//
#include <hip/hip_runtime.h>
#include <hip/hip_bf16.h>
#include <math.h>

#define BB 2
#define NN 2048
#define QD 1024
#define CTX_LEN 77
#define TCD 768
#define NUM_PROMPT 64
#define PD 1024
#define HEADS 8
#define DIM_HEAD 64
#define INNER 512
#define JTOT (CTX_LEN + NUM_PROMPT + NN)   // 2189
#define SCALE 0.125f
#define MTOT (BB * NN)                     // 4096
#define JSPLIT 1088

typedef unsigned short u16;
typedef unsigned int u32;
typedef __attribute__((ext_vector_type(8))) short bf16x8;
typedef __attribute__((ext_vector_type(4))) float f32x4;

__device__ __forceinline__ u32 pack_split(float f) {
  u32 u = __builtin_bit_cast(u32, f);
  u32 hi = u & 0xffff0000u;
  float lo = f - __builtin_bit_cast(float, hi);
  u32 ul = __builtin_bit_cast(u32, lo);
  return __builtin_amdgcn_perm(ul, u, 0x07060302u);
}
__device__ __forceinline__ void split2(float f, u16& h, u16& l) {
  u32 u = __builtin_bit_cast(u32, f);
  u32 hm = u & 0xffff0000u;
  float lo = f - __builtin_bit_cast(float, hm);
  h = (u16)(u >> 16);
  l = (u16)(__builtin_bit_cast(u32, lo) >> 16);
}
__device__ __forceinline__ void unpack8(const u32* u, bf16x8& hf, bf16x8& lf) {
  union { u32 w[4]; bf16x8 v; } H, L;
#pragma unroll
  for (int i = 0; i < 4; ++i) {
    H.w[i] = __builtin_amdgcn_perm(u[2 * i + 1], u[2 * i], 0x05040100u);
    L.w[i] = __builtin_amdgcn_perm(u[2 * i + 1], u[2 * i], 0x07060302u);
  }
  hf = H.v; lf = L.v;
}

__global__ __launch_bounds__(256) void transpose_pack(
    const float* __restrict__ src, u16* __restrict__ dh, u16* __restrict__ dl,
    int K, int N) {
  __shared__ u32 T[32][33];
  const int t = threadIdx.x;
  const int k0 = blockIdx.y * 32, n0 = blockIdx.x * 32;
#pragma unroll
  for (int i = 0; i < 4; ++i) {
    int e = t + i * 256;
    int kr = e >> 5, nc = e & 31;
    T[kr][nc] = pack_split(src[(size_t)(k0 + kr) * N + n0 + nc]);
  }
  __syncthreads();
#pragma unroll
  for (int i = 0; i < 4; ++i) {
    int e = t + i * 256;
    int nr = e >> 5, kc = e & 31;
    u32 w = T[kc][nr];
    size_t idx = (size_t)(n0 + nr) * K + k0 + kc;
    dh[idx] = (u16)(w & 0xffff);
    dl[idx] = (u16)(w >> 16);
  }
}

// ---------------- split-bf16 MFMA GEMM, 128x64 tiles, software-pipelined ----------------
#define GST 20

template <int MODE, bool AF32>
__global__ __launch_bounds__(256) void gemm_mfma(
    const float* __restrict__ Af, const u16* __restrict__ Agh, const u16* __restrict__ Agl,
    const u16* __restrict__ Bgh, const u16* __restrict__ Bgl,
    u16* __restrict__ O1h, u16* __restrict__ O1l,
    u16* __restrict__ O2h, u16* __restrict__ O2l,
    float* __restrict__ Of, const float* __restrict__ bias,
    int M, int K, int Ntot) {
  __shared__ __align__(16) u32 Ah_s[128 * GST];
  __shared__ __align__(16) u32 Al_s[128 * GST];
  __shared__ __align__(16) u32 Bh_s[64 * GST];
  __shared__ __align__(16) u32 Bl_s[64 * GST];

  const int t = threadIdx.x;
  const int w = t >> 6, lane = t & 63;
  const int m16 = lane & 15, quad = lane >> 4;
  const int wm = w >> 1, wn = w & 1;
  const int bm = blockIdx.y * 128, bn = blockIdx.x * 64;

  const int arow = t >> 1, ahalf = t & 1;
  const int brow = t >> 2, bchunk = t & 3;
  const bool avalid = (bm + arow) < M;
  const int adst = arow * GST + ahalf * 8;
  const int bdst = brow * GST + bchunk * 4;
  const float* apf = Af ? (Af + (size_t)(bm + arow) * K + ahalf * 16) : nullptr;
  const u16* aph = Agh ? (Agh + (size_t)(bm + arow) * K + ahalf * 16) : nullptr;
  const u16* apl = Agl ? (Agl + (size_t)(bm + arow) * K + ahalf * 16) : nullptr;
  const u16* bph = Bgh + (size_t)(bn + brow) * K + bchunk * 8;
  const u16* bpl = Bgl + (size_t)(bn + brow) * K + bchunk * 8;

  const uint4 Z = {0u, 0u, 0u, 0u};
  const float4 ZF = {0.f, 0.f, 0.f, 0.f};

  f32x4 acc[4][2];
#pragma unroll
  for (int i = 0; i < 4; ++i)
#pragma unroll
    for (int j = 0; j < 2; ++j) acc[i][j] = (f32x4){0.f, 0.f, 0.f, 0.f};

  // prefetch holders
  float4 fA[4];
  uint4 pA[4];   // [0..1]=hi, [2..3]=lo
  uint4 pB[2];

  // initial prefetch (k0 = 0)
  if (AF32) {
#pragma unroll
    for (int j = 0; j < 4; ++j) fA[j] = avalid ? *(const float4*)(apf + j * 4) : ZF;
  } else {
    pA[0] = avalid ? *(const uint4*)(aph) : Z;
    pA[1] = avalid ? *(const uint4*)(aph + 8) : Z;
    pA[2] = avalid ? *(const uint4*)(apl) : Z;
    pA[3] = avalid ? *(const uint4*)(apl + 8) : Z;
  }
  pB[0] = *(const uint4*)(bph);
  pB[1] = *(const uint4*)(bpl);

  for (int k0 = 0; k0 < K; k0 += 32) {
    // ---- stage from registers ----
    if (AF32) {
      const float* f = (const float*)fA;
      u32 h[8], l[8];
#pragma unroll
      for (int e = 0; e < 8; ++e) {
        u32 u0 = __builtin_bit_cast(u32, f[2 * e]);
        u32 u1 = __builtin_bit_cast(u32, f[2 * e + 1]);
        h[e] = __builtin_amdgcn_perm(u1, u0, 0x07060302u);
        float lo0 = f[2 * e] - __builtin_bit_cast(float, u0 & 0xffff0000u);
        float lo1 = f[2 * e + 1] - __builtin_bit_cast(float, u1 & 0xffff0000u);
        l[e] = __builtin_amdgcn_perm(__builtin_bit_cast(u32, lo1),
                                     __builtin_bit_cast(u32, lo0), 0x07060302u);
      }
      *(uint4*)&Ah_s[adst] = (uint4){h[0], h[1], h[2], h[3]};
      *(uint4*)&Ah_s[adst + 4] = (uint4){h[4], h[5], h[6], h[7]};
      *(uint4*)&Al_s[adst] = (uint4){l[0], l[1], l[2], l[3]};
      *(uint4*)&Al_s[adst + 4] = (uint4){l[4], l[5], l[6], l[7]};
    } else {
      *(uint4*)&Ah_s[adst]     = pA[0];
      *(uint4*)&Ah_s[adst + 4] = pA[1];
      *(uint4*)&Al_s[adst]     = pA[2];
      *(uint4*)&Al_s[adst + 4] = pA[3];
    }
    *(uint4*)&Bh_s[bdst] = pB[0];
    *(uint4*)&Bl_s[bdst] = pB[1];
    __syncthreads();

    // ---- prefetch next k-step (overlaps frag reads + MFMA) ----
    const bool more = (k0 + 32) < K;
    float4 nfA[4];
    uint4 npA[4], npB[2];
    if (more) {
      int kn = k0 + 32;
      if (AF32) {
#pragma unroll
        for (int j = 0; j < 4; ++j)
          nfA[j] = avalid ? *(const float4*)(apf + kn + j * 4) : ZF;
      } else {
        npA[0] = avalid ? *(const uint4*)(aph + kn) : Z;
        npA[1] = avalid ? *(const uint4*)(aph + kn + 8) : Z;
        npA[2] = avalid ? *(const uint4*)(apl + kn) : Z;
        npA[3] = avalid ? *(const uint4*)(apl + kn + 8) : Z;
      }
      npB[0] = *(const uint4*)(bph + kn);
      npB[1] = *(const uint4*)(bpl + kn);
    }

    // ---- fragments + MFMA ----
    bf16x8 ah[4], al[4], bh[2], bl[2];
#pragma unroll
    for (int mt = 0; mt < 4; ++mt) {
      int off = (wm * 64 + mt * 16 + m16) * GST + quad * 4;
      ah[mt] = *(const bf16x8*)&Ah_s[off];
      al[mt] = *(const bf16x8*)&Al_s[off];
    }
#pragma unroll
    for (int nt = 0; nt < 2; ++nt) {
      int off = (wn * 32 + nt * 16 + m16) * GST + quad * 4;
      bh[nt] = *(const bf16x8*)&Bh_s[off];
      bl[nt] = *(const bf16x8*)&Bl_s[off];
    }
#pragma unroll
    for (int mt = 0; mt < 4; ++mt)
#pragma unroll
      for (int nt = 0; nt < 2; ++nt) {
        acc[mt][nt] = __builtin_amdgcn_mfma_f32_16x16x32_bf16(ah[mt], bh[nt], acc[mt][nt], 0, 0, 0);
        acc[mt][nt] = __builtin_amdgcn_mfma_f32_16x16x32_bf16(ah[mt], bl[nt], acc[mt][nt], 0, 0, 0);
        acc[mt][nt] = __builtin_amdgcn_mfma_f32_16x16x32_bf16(al[mt], bh[nt], acc[mt][nt], 0, 0, 0);
      }
    __syncthreads();

    if (more) {
      if (AF32) {
#pragma unroll
        for (int j = 0; j < 4; ++j) fA[j] = nfA[j];
      } else {
#pragma unroll
        for (int j = 0; j < 4; ++j) pA[j] = npA[j];
      }
      pB[0] = npB[0]; pB[1] = npB[1];
    }
  }

  // ---- epilogue ----
#pragma unroll
  for (int mt = 0; mt < 4; ++mt)
#pragma unroll
    for (int nt = 0; nt < 2; ++nt)
#pragma unroll
      for (int r = 0; r < 4; ++r) {
        int gm = bm + wm * 64 + mt * 16 + quad * 4 + r;
        int gn = bn + wn * 32 + nt * 16 + m16;
        float v = acc[mt][nt][r];
        u16 sh, sl;
        if (MODE == 0) {
          if (gm < M) {
            split2(v, sh, sl);
            size_t idx = (size_t)gm * Ntot + gn;
            O1h[idx] = sh; O1l[idx] = sl;
          }
        } else if (MODE == 1) {
          if (gn < TCD) {
            split2(v, sh, sl);
            size_t row = (size_t)(gm >> 11) * JTOT + 141 + (gm & 2047);
            O1h[row * TCD + gn] = sh; O1l[row * TCD + gn] = sl;
          } else {
            split2(v * SCALE, sh, sl);
            size_t idx = (size_t)gm * INNER + (gn - TCD);
            O2h[idx] = sh; O2l[idx] = sl;
          }
        } else if (MODE == 2) {
          if (gm < M) {
            split2(v, sh, sl);
            if (gn < INNER) {
              size_t idx = (size_t)gm * INNER + gn;
              O1h[idx] = sh; O1l[idx] = sl;
            } else {
              size_t idx = (size_t)gm * INNER + (gn - INNER);
              O2h[idx] = sh; O2l[idx] = sl;
            }
          }
        } else {
          Of[(size_t)gm * QD + gn] = v + bias[gn];
        }
      }
}

__global__ __launch_bounds__(256) void copy_ctx_kernel(
    const float* __restrict__ context, const u16* __restrict__ pch,
    const u16* __restrict__ pcl, u16* __restrict__ ch, u16* __restrict__ cl) {
  int idx = blockIdx.x * 256 + threadIdx.x;
  const int total = BB * 141 * TCD;
  if (idx >= total) return;
  int c = idx % TCD;
  int r = (idx / TCD) % 141;
  int b = idx / (141 * TCD);
  size_t dst = ((size_t)b * JTOT + r) * TCD + c;
  if (r < CTX_LEN) {
    u16 sh, sl;
    split2(context[((size_t)b * CTX_LEN + r) * TCD + c], sh, sl);
    ch[dst] = sh; cl[dst] = sl;
  } else {
    size_t s = (size_t)(r - CTX_LEN) * TCD + c;
    ch[dst] = pch[s]; cl[dst] = pcl[s];
  }
}

// ---------------- flash attention: J-split, 2 barriers/tile, pipelined ----------------
#define AST 36
#define PST 68

__global__ __launch_bounds__(256) void attn_mfma(
    const u16* __restrict__ qgh, const u16* __restrict__ qgl,
    const u16* __restrict__ kgh, const u16* __restrict__ kgl,
    const u16* __restrict__ vgh, const u16* __restrict__ vgl,
    float* __restrict__ Op, float* __restrict__ Mp, float* __restrict__ Lp) {
  __shared__ __align__(16) u32 Kh[64 * AST];
  __shared__ __align__(16) u32 Kl[64 * AST];
  __shared__ __align__(16) u32 Vh[64 * AST];
  __shared__ __align__(16) u32 Vl[64 * AST];
  __shared__ __align__(16) u32 Pb[4][16 * PST];

  const int t = threadIdx.x;
  const int w = t >> 6, lane = t & 63;
  const int m16 = lane & 15, quad = lane >> 4;
  const int blk = blockIdx.x;
  const int bh = blk & 15;
  const int s = (blk >> 4) & 1;
  const int qt = blk >> 5;
  const int b = bh >> 3, h = bh & 7;
  const int q0 = qt * 64 + w * 16;
  const int jstart = s * JSPLIT;
  const int jend = s ? JTOT : JSPLIT;

  const u16* qrh = qgh + ((size_t)(b * NN + q0 + m16)) * INNER + h * 64;
  const u16* qrl = qgl + ((size_t)(b * NN + q0 + m16)) * INNER + h * 64;
  bf16x8 qfh[2], qfl[2];
#pragma unroll
  for (int ks = 0; ks < 2; ++ks) {
    qfh[ks] = *(const bf16x8*)(qrh + ks * 32 + quad * 8);
    qfl[ks] = *(const bf16x8*)(qrl + ks * 32 + quad * 8);
  }

  f32x4 O[4] = {{0.f,0.f,0.f,0.f},{0.f,0.f,0.f,0.f},{0.f,0.f,0.f,0.f},{0.f,0.f,0.f,0.f}};
  float mr[4], lr[4];
#pragma unroll
  for (int r = 0; r < 4; ++r) { mr[r] = -INFINITY; lr[r] = 0.f; }

  const size_t kvbase = (size_t)b * JTOT * INNER + h * 64;
  const uint4 Z = {0u, 0u, 0u, 0u};
  u32* P = Pb[w];
  const int krow = t >> 2, kch = t & 3;
  const int vp = t & 31, vdch = t >> 5;

  // prefetch holders: cK[0..1]=K hi, [2..3]=K lo; cV[0]=ja hi, [1]=jb hi, [2]=ja lo, [3]=jb lo
  uint4 cK[4], cV[4];
  {
    int jg = jstart + krow;
    bool ok = jg < JTOT;
    size_t off = kvbase + (size_t)jg * INNER + kch * 16;
    cK[0] = ok ? *(const uint4*)(kgh + off) : Z;
    cK[1] = ok ? *(const uint4*)(kgh + off + 8) : Z;
    cK[2] = ok ? *(const uint4*)(kgl + off) : Z;
    cK[3] = ok ? *(const uint4*)(kgl + off + 8) : Z;
    int ja = jstart + 2 * vp, jb = ja + 1;
    size_t offa = kvbase + (size_t)ja * INNER + vdch * 8;
    cV[0] = (ja < JTOT) ? *(const uint4*)(vgh + offa) : Z;
    cV[1] = (jb < JTOT) ? *(const uint4*)(vgh + offa + INNER) : Z;
    cV[2] = (ja < JTOT) ? *(const uint4*)(vgl + offa) : Z;
    cV[3] = (jb < JTOT) ? *(const uint4*)(vgl + offa + INNER) : Z;
  }

#pragma unroll 1
  for (int j0 = jstart; j0 < jend; j0 += 64) {
    __syncthreads();   // previous tile's frag reads done; LDS writable
    // ---- stage K from regs ----
    {
      int d = krow * AST + kch * 8;
      *(uint4*)&Kh[d]     = cK[0];
      *(uint4*)&Kh[d + 4] = cK[1];
      *(uint4*)&Kl[d]     = cK[2];
      *(uint4*)&Kl[d + 4] = cK[3];
    }
    // ---- stage V from regs (pair-transpose perms) ----
    {
      const u32* a0 = (const u32*)&cV[0]; const u32* b0 = (const u32*)&cV[1];
      const u32* a1 = (const u32*)&cV[2]; const u32* b1 = (const u32*)&cV[3];
#pragma unroll
      for (int i = 0; i < 4; ++i) {
        Vh[(vdch * 8 + 2 * i) * AST + vp]     = __builtin_amdgcn_perm(b0[i], a0[i], 0x05040100u);
        Vh[(vdch * 8 + 2 * i + 1) * AST + vp] = __builtin_amdgcn_perm(b0[i], a0[i], 0x07060302u);
        Vl[(vdch * 8 + 2 * i) * AST + vp]     = __builtin_amdgcn_perm(b1[i], a1[i], 0x05040100u);
        Vl[(vdch * 8 + 2 * i + 1) * AST + vp] = __builtin_amdgcn_perm(b1[i], a1[i], 0x07060302u);
      }
    }
    __syncthreads();

    // ---- prefetch next tile (overlaps all compute below) ----
    const bool more = (j0 + 64) < jend;
    uint4 nK[4], nV[4];
    if (more) {
      int jn = j0 + 64;
      int jg = jn + krow;
      bool ok = jg < JTOT;
      size_t off = kvbase + (size_t)jg * INNER + kch * 16;
      nK[0] = ok ? *(const uint4*)(kgh + off) : Z;
      nK[1] = ok ? *(const uint4*)(kgh + off + 8) : Z;
      nK[2] = ok ? *(const uint4*)(kgl + off) : Z;
      nK[3] = ok ? *(const uint4*)(kgl + off + 8) : Z;
      int ja = jn + 2 * vp, jb = ja + 1;
      size_t offa = kvbase + (size_t)ja * INNER + vdch * 8;
      nV[0] = (ja < JTOT) ? *(const uint4*)(vgh + offa) : Z;
      nV[1] = (jb < JTOT) ? *(const uint4*)(vgh + offa + INNER) : Z;
      nV[2] = (ja < JTOT) ? *(const uint4*)(vgl + offa) : Z;
      nV[3] = (jb < JTOT) ? *(const uint4*)(vgl + offa + INNER) : Z;
    }

    // ---- S = Q K^T ----
    f32x4 S[4];
#pragma unroll
    for (int jt = 0; jt < 4; ++jt) {
      f32x4 acc = {0.f, 0.f, 0.f, 0.f};
#pragma unroll
      for (int ks = 0; ks < 2; ++ks) {
        int off = (jt * 16 + m16) * AST + ks * 16 + quad * 4;
        bf16x8 kfh = *(const bf16x8*)&Kh[off];
        bf16x8 kfl = *(const bf16x8*)&Kl[off];
        acc = __builtin_amdgcn_mfma_f32_16x16x32_bf16(qfh[ks], kfh, acc, 0, 0, 0);
        acc = __builtin_amdgcn_mfma_f32_16x16x32_bf16(qfh[ks], kfl, acc, 0, 0, 0);
        acc = __builtin_amdgcn_mfma_f32_16x16x32_bf16(qfl[ks], kfh, acc, 0, 0, 0);
      }
      S[jt] = acc;
    }
#pragma unroll
    for (int jt = 0; jt < 4; ++jt) {
      int jc = j0 + jt * 16 + m16;
      if (jc >= JTOT) {
#pragma unroll
        for (int r = 0; r < 4; ++r) S[jt][r] = -INFINITY;
      }
    }

    // ---- online softmax ----
    float pj[4][4];
#pragma unroll
    for (int r = 0; r < 4; ++r) {
      float mx = fmaxf(fmaxf(S[0][r], S[1][r]), fmaxf(S[2][r], S[3][r]));
#pragma unroll
      for (int off = 1; off < 16; off <<= 1)
        mx = fmaxf(mx, __shfl_xor(mx, off, 64));
      float mnew = fmaxf(mr[r], mx);
      float alpha = __expf(mr[r] - mnew);
      mr[r] = mnew;
      float rs = 0.f;
#pragma unroll
      for (int jt = 0; jt < 4; ++jt) {
        float p = __expf(S[jt][r] - mnew);
        pj[jt][r] = p;
        rs += p;
      }
#pragma unroll
      for (int off = 1; off < 16; off <<= 1)
        rs += __shfl_xor(rs, off, 64);
      lr[r] = lr[r] * alpha + rs;
#pragma unroll
      for (int nt = 0; nt < 4; ++nt) O[nt][r] *= alpha;
    }

    // ---- P round-trip (wave-private) ----
#pragma unroll
    for (int jt = 0; jt < 4; ++jt)
#pragma unroll
      for (int r = 0; r < 4; ++r)
        P[(quad * 4 + r) * PST + jt * 16 + m16] = pack_split(pj[jt][r]);

    bf16x8 ph[2], pl[2];
#pragma unroll
    for (int ks = 0; ks < 2; ++ks) {
      const u32* pp = &P[m16 * PST + ks * 32 + quad * 8];
      uint4 a = *(const uint4*)pp, c = *(const uint4*)(pp + 4);
      u32 u[8] = {a.x, a.y, a.z, a.w, c.x, c.y, c.z, c.w};
      unpack8(u, ph[ks], pl[ks]);
    }

    // ---- O += P V ----
#pragma unroll
    for (int nt = 0; nt < 4; ++nt)
#pragma unroll
      for (int ks = 0; ks < 2; ++ks) {
        int off = (nt * 16 + m16) * AST + ks * 16 + quad * 4;
        bf16x8 vfh = *(const bf16x8*)&Vh[off];
        bf16x8 vfl = *(const bf16x8*)&Vl[off];
        O[nt] = __builtin_amdgcn_mfma_f32_16x16x32_bf16(ph[ks], vfh, O[nt], 0, 0, 0);
        O[nt] = __builtin_amdgcn_mfma_f32_16x16x32_bf16(ph[ks], vfl, O[nt], 0, 0, 0);
        O[nt] = __builtin_amdgcn_mfma_f32_16x16x32_bf16(pl[ks], vfh, O[nt], 0, 0, 0);
      }

    if (more) {
#pragma unroll
      for (int i = 0; i < 4; ++i) { cK[i] = nK[i]; cV[i] = nV[i]; }
    }
  }

  // ---- epilogue: unnormalized partials + (m,l) ----
#pragma unroll
  for (int nt = 0; nt < 4; ++nt)
#pragma unroll
    for (int r = 0; r < 4; ++r) {
      int row = q0 + quad * 4 + r;
      size_t idx = (size_t)s * MTOT * INNER + ((size_t)(b * NN + row)) * INNER +
                   h * 64 + nt * 16 + m16;
      Op[idx] = O[nt][r];
    }
  if (m16 == 0) {
#pragma unroll
    for (int r = 0; r < 4; ++r) {
      int row = q0 + quad * 4 + r;
      size_t idx = (size_t)(s * MTOT + b * NN + row) * HEADS + h;
      Mp[idx] = mr[r];
      Lp[idx] = lr[r];
    }
  }
}

// ---------------- combine 2 partials -> ao planes ----------------
__global__ __launch_bounds__(256) void attn_combine(
    const float* __restrict__ Op, const float* __restrict__ Mp,
    const float* __restrict__ Lp, u16* __restrict__ aoh, u16* __restrict__ aol) {
  int idx = blockIdx.x * 256 + threadIdx.x;
  int c4 = idx * 4;
  int row = c4 >> 9;
  int c = c4 & 511;
  int h = c >> 6;
  size_t mi = (size_t)row * HEADS + h;
  float m0 = Mp[mi], m1 = Mp[(size_t)MTOT * HEADS + mi];
  float l0 = Lp[mi], l1 = Lp[(size_t)MTOT * HEADS + mi];
  float ms = fmaxf(m0, m1);
  float w0 = __expf(m0 - ms), w1 = __expf(m1 - ms);
  float inv = 1.f / (w0 * l0 + w1 * l1);
  float4 o0 = *(const float4*)&Op[(size_t)row * INNER + c];
  float4 o1 = *(const float4*)&Op[(size_t)MTOT * INNER + (size_t)row * INNER + c];
  float vals[4] = {
    (w0 * o0.x + w1 * o1.x) * inv, (w0 * o0.y + w1 * o1.y) * inv,
    (w0 * o0.z + w1 * o1.z) * inv, (w0 * o0.w + w1 * o1.w) * inv };
#pragma unroll
  for (int i = 0; i < 4; ++i) {
    u16 sh, sl;
    split2(vals[i], sh, sl);
    size_t d = (size_t)row * INNER + c + i;
    aoh[d] = sh; aol[d] = sl;
  }
}

// ---------------- launch ----------------
extern "C" void kernel_launch(void* const* d_in, const int* in_sizes, int n_in,
                              void* d_out, int out_size, void* d_ws, size_t ws_size,
                              hipStream_t stream) {
  const float* x        = (const float*)d_in[0];
  const float* context  = (const float*)d_in[1];
  const float* prompt   = (const float*)d_in[2];
  const float* w_prompt = (const float*)d_in[3];
  const float* w_img    = (const float*)d_in[4];
  const float* w_q      = (const float*)d_in[5];
  const float* w_k      = (const float*)d_in[6];
  const float* w_v      = (const float*)d_in[7];
  const float* w_out    = (const float*)d_in[8];
  const float* b_out    = (const float*)d_in[9];
  float* out = (float*)d_out;

  const int M = MTOT;
  const int MJ = BB * JTOT;

  u16* p = (u16*)d_ws;
  const size_t qN = (size_t)M * INNER, ctxN = (size_t)MJ * TCD, kvN = (size_t)MJ * INNER;
  u16* qh  = p; p += qN;  u16* ql  = p; p += qN;
  u16* pch = p; p += (size_t)NUM_PROMPT * TCD;
  u16* pcl = p; p += (size_t)NUM_PROMPT * TCD;
  u16* cth = p; p += ctxN; u16* ctl = p; p += ctxN;
  u16* kh  = p; p += kvN;  u16* kl  = p; p += kvN;
  u16* vh  = p; p += kvN;  u16* vl  = p; p += kvN;
  u16* aoh = p; p += qN;   u16* aol = p; p += qN;
  u16* WtPh = p; p += (size_t)TCD * PD;            u16* WtPl = p; p += (size_t)TCD * PD;
  u16* WtAh = p; p += (size_t)(TCD + INNER) * QD;  u16* WtAl = p; p += (size_t)(TCD + INNER) * QD;
  u16* WtBh = p; p += (size_t)(2 * INNER) * TCD;   u16* WtBl = p; p += (size_t)(2 * INNER) * TCD;
  u16* WtOh = p; p += (size_t)QD * INNER;          u16* WtOl = p; p += (size_t)QD * INNER;
  float* Op = (float*)p;
  float* Mp = Op + (size_t)2 * M * INNER;
  float* Lp = Mp + (size_t)2 * M * HEADS;

  transpose_pack<<<dim3(TCD / 32, PD / 32), 256, 0, stream>>>(w_prompt, WtPh, WtPl, PD, TCD);
  transpose_pack<<<dim3(TCD / 32, QD / 32), 256, 0, stream>>>(w_img, WtAh, WtAl, QD, TCD);
  transpose_pack<<<dim3(INNER / 32, QD / 32), 256, 0, stream>>>(
      w_q, WtAh + (size_t)TCD * QD, WtAl + (size_t)TCD * QD, QD, INNER);
  transpose_pack<<<dim3(INNER / 32, TCD / 32), 256, 0, stream>>>(w_k, WtBh, WtBl, TCD, INNER);
  transpose_pack<<<dim3(INNER / 32, TCD / 32), 256, 0, stream>>>(
      w_v, WtBh + (size_t)INNER * TCD, WtBl + (size_t)INNER * TCD, TCD, INNER);
  transpose_pack<<<dim3(QD / 32, INNER / 32), 256, 0, stream>>>(w_out, WtOh, WtOl, INNER, QD);

  gemm_mfma<0, true><<<dim3(TCD / 64, 1), 256, 0, stream>>>(
      prompt, nullptr, nullptr, WtPh, WtPl, pch, pcl, nullptr, nullptr, nullptr, nullptr,
      NUM_PROMPT, PD, TCD);
  copy_ctx_kernel<<<(BB * 141 * TCD + 255) / 256, 256, 0, stream>>>(context, pch, pcl, cth, ctl);
  gemm_mfma<1, true><<<dim3((TCD + INNER) / 64, M / 128), 256, 0, stream>>>(
      x, nullptr, nullptr, WtAh, WtAl, cth, ctl, qh, ql, nullptr, nullptr,
      M, QD, TCD + INNER);
  gemm_mfma<2, false><<<dim3((2 * INNER) / 64, (MJ + 127) / 128), 256, 0, stream>>>(
      nullptr, cth, ctl, WtBh, WtBl, kh, kl, vh, vl, nullptr, nullptr,
      MJ, TCD, 2 * INNER);
  attn_mfma<<<BB * HEADS * (NN / 64) * 2, 256, 0, stream>>>(
      qh, ql, kh, kl, vh, vl, Op, Mp, Lp);
  attn_combine<<<(M * INNER / 4) / 256, 256, 0, stream>>>(Op, Mp, Lp, aoh, aol);
  gemm_mfma<3, false><<<dim3(QD / 64, M / 128), 256, 0, stream>>>(
      nullptr, aoh, aol, WtOh, WtOl, nullptr, nullptr, nullptr, nullptr, out, b_out,
      M, INNER, QD);
}

// Round 10
// 410.428 us; speedup vs baseline: 2.5943x; 2.5943x over previous
//
#include <hip/hip_runtime.h>
#include <hip/hip_bf16.h>
#include <math.h>

#define BB 2
#define NN 2048
#define QD 1024
#define CTX_LEN 77
#define TCD 768
#define NUM_PROMPT 64
#define PD 1024
#define HEADS 8
#define DIM_HEAD 64
#define INNER 512
#define JTOT (CTX_LEN + NUM_PROMPT + NN)   // 2189
#define SCALE 0.125f
#define MTOT (BB * NN)                     // 4096

typedef unsigned short u16;
typedef unsigned int u32;
typedef __attribute__((ext_vector_type(8))) short bf16x8;
typedef __attribute__((ext_vector_type(4))) float f32x4;

__device__ __forceinline__ u32 pack_split(float f) {   // interleaved: low16=hi, high16=lo
  u32 u = __builtin_bit_cast(u32, f);
  u32 hi = u & 0xffff0000u;
  float lo = f - __builtin_bit_cast(float, hi);
  u32 ul = __builtin_bit_cast(u32, lo);
  return __builtin_amdgcn_perm(ul, u, 0x07060302u);
}
__device__ __forceinline__ void split2(float f, u16& h, u16& l) {
  u32 u = __builtin_bit_cast(u32, f);
  u32 hm = u & 0xffff0000u;
  float lo = f - __builtin_bit_cast(float, hm);
  h = (u16)(u >> 16);
  l = (u16)(__builtin_bit_cast(u32, lo) >> 16);
}
__device__ __forceinline__ void unpack8(const u32* u, bf16x8& hf, bf16x8& lf) {
  union { u32 w[4]; bf16x8 v; } H, L;
#pragma unroll
  for (int i = 0; i < 4; ++i) {
    H.w[i] = __builtin_amdgcn_perm(u[2 * i + 1], u[2 * i], 0x05040100u);
    L.w[i] = __builtin_amdgcn_perm(u[2 * i + 1], u[2 * i], 0x07060302u);
  }
  hf = H.v; lf = L.v;
}

__global__ __launch_bounds__(256) void transpose_pack(
    const float* __restrict__ src, u16* __restrict__ dh, u16* __restrict__ dl,
    int K, int N) {
  __shared__ u32 T[32][33];
  const int t = threadIdx.x;
  const int k0 = blockIdx.y * 32, n0 = blockIdx.x * 32;
#pragma unroll
  for (int i = 0; i < 4; ++i) {
    int e = t + i * 256;
    int kr = e >> 5, nc = e & 31;
    T[kr][nc] = pack_split(src[(size_t)(k0 + kr) * N + n0 + nc]);
  }
  __syncthreads();
#pragma unroll
  for (int i = 0; i < 4; ++i) {
    int e = t + i * 256;
    int nr = e >> 5, kc = e & 31;
    u32 w = T[kc][nr];
    size_t idx = (size_t)(n0 + nr) * K + k0 + kc;
    dh[idx] = (u16)(w & 0xffff);
    dl[idx] = (u16)(w >> 16);
  }
}

// ---------------- split-bf16 MFMA GEMM, 128x64 tiles (R8 structure, no prefetch) ----------------
// MODE 0: plane output -> O1h/O1l
// MODE 1: gn<TCD -> ctx planes (row remap); else q interleaved u32 (x SCALE) -> Oi1
// MODE 2: gn<INNER -> k interleaved -> Oi1; else v interleaved -> Oi2
// MODE 3: f32 out + bias
#define GST 20

template <int MODE, bool AF32>
__global__ __launch_bounds__(256) void gemm_mfma(
    const float* __restrict__ Af, const u16* __restrict__ Agh, const u16* __restrict__ Agl,
    const u16* __restrict__ Bgh, const u16* __restrict__ Bgl,
    u16* __restrict__ O1h, u16* __restrict__ O1l,
    u32* __restrict__ Oi1, u32* __restrict__ Oi2,
    float* __restrict__ Of, const float* __restrict__ bias,
    int M, int K, int Ntot) {
  __shared__ __align__(16) u32 Ah_s[128 * GST];
  __shared__ __align__(16) u32 Al_s[128 * GST];
  __shared__ __align__(16) u32 Bh_s[64 * GST];
  __shared__ __align__(16) u32 Bl_s[64 * GST];

  const int t = threadIdx.x;
  const int w = t >> 6, lane = t & 63;
  const int m16 = lane & 15, quad = lane >> 4;
  const int wm = w >> 1, wn = w & 1;
  const int bm = blockIdx.y * 128, bn = blockIdx.x * 64;

  const int arow = t >> 1, ahalf = t & 1;
  const int brow = t >> 2, bchunk = t & 3;
  const bool avalid = (bm + arow) < M;
  const int adst = arow * GST + ahalf * 8;
  const int bdst = brow * GST + bchunk * 4;
  const float* apf = Af ? (Af + (size_t)(bm + arow) * K + ahalf * 16) : nullptr;
  const u16* aph = Agh ? (Agh + (size_t)(bm + arow) * K + ahalf * 16) : nullptr;
  const u16* apl = Agl ? (Agl + (size_t)(bm + arow) * K + ahalf * 16) : nullptr;
  const u16* bph = Bgh + (size_t)(bn + brow) * K + bchunk * 8;
  const u16* bpl = Bgl + (size_t)(bn + brow) * K + bchunk * 8;

  f32x4 acc[4][2];
#pragma unroll
  for (int i = 0; i < 4; ++i)
#pragma unroll
    for (int j = 0; j < 2; ++j) acc[i][j] = (f32x4){0.f, 0.f, 0.f, 0.f};

  const uint4 Z = {0u, 0u, 0u, 0u};

  for (int k0 = 0; k0 < K; k0 += 32) {
    if (AF32) {
      float4 fr[4];
#pragma unroll
      for (int j = 0; j < 4; ++j)
        fr[j] = avalid ? *(const float4*)(apf + k0 + j * 4) : (float4){0.f, 0.f, 0.f, 0.f};
      const float* f = (const float*)fr;
      u32 h[8], l[8];
#pragma unroll
      for (int e = 0; e < 8; ++e) {
        u32 u0 = __builtin_bit_cast(u32, f[2 * e]);
        u32 u1 = __builtin_bit_cast(u32, f[2 * e + 1]);
        h[e] = __builtin_amdgcn_perm(u1, u0, 0x07060302u);
        float lo0 = f[2 * e] - __builtin_bit_cast(float, u0 & 0xffff0000u);
        float lo1 = f[2 * e + 1] - __builtin_bit_cast(float, u1 & 0xffff0000u);
        l[e] = __builtin_amdgcn_perm(__builtin_bit_cast(u32, lo1),
                                     __builtin_bit_cast(u32, lo0), 0x07060302u);
      }
      *(uint4*)&Ah_s[adst] = (uint4){h[0], h[1], h[2], h[3]};
      *(uint4*)&Ah_s[adst + 4] = (uint4){h[4], h[5], h[6], h[7]};
      *(uint4*)&Al_s[adst] = (uint4){l[0], l[1], l[2], l[3]};
      *(uint4*)&Al_s[adst + 4] = (uint4){l[4], l[5], l[6], l[7]};
    } else {
      *(uint4*)&Ah_s[adst]     = avalid ? *(const uint4*)(aph + k0) : Z;
      *(uint4*)&Ah_s[adst + 4] = avalid ? *(const uint4*)(aph + k0 + 8) : Z;
      *(uint4*)&Al_s[adst]     = avalid ? *(const uint4*)(apl + k0) : Z;
      *(uint4*)&Al_s[adst + 4] = avalid ? *(const uint4*)(apl + k0 + 8) : Z;
    }
    *(uint4*)&Bh_s[bdst] = *(const uint4*)(bph + k0);
    *(uint4*)&Bl_s[bdst] = *(const uint4*)(bpl + k0);
    __syncthreads();

    bf16x8 ah[4], al[4], bh[2], bl[2];
#pragma unroll
    for (int mt = 0; mt < 4; ++mt) {
      int off = (wm * 64 + mt * 16 + m16) * GST + quad * 4;
      ah[mt] = *(const bf16x8*)&Ah_s[off];
      al[mt] = *(const bf16x8*)&Al_s[off];
    }
#pragma unroll
    for (int nt = 0; nt < 2; ++nt) {
      int off = (wn * 32 + nt * 16 + m16) * GST + quad * 4;
      bh[nt] = *(const bf16x8*)&Bh_s[off];
      bl[nt] = *(const bf16x8*)&Bl_s[off];
    }
#pragma unroll
    for (int mt = 0; mt < 4; ++mt)
#pragma unroll
      for (int nt = 0; nt < 2; ++nt) {
        acc[mt][nt] = __builtin_amdgcn_mfma_f32_16x16x32_bf16(ah[mt], bh[nt], acc[mt][nt], 0, 0, 0);
        acc[mt][nt] = __builtin_amdgcn_mfma_f32_16x16x32_bf16(ah[mt], bl[nt], acc[mt][nt], 0, 0, 0);
        acc[mt][nt] = __builtin_amdgcn_mfma_f32_16x16x32_bf16(al[mt], bh[nt], acc[mt][nt], 0, 0, 0);
      }
    __syncthreads();
  }

#pragma unroll
  for (int mt = 0; mt < 4; ++mt)
#pragma unroll
    for (int nt = 0; nt < 2; ++nt)
#pragma unroll
      for (int r = 0; r < 4; ++r) {
        int gm = bm + wm * 64 + mt * 16 + quad * 4 + r;
        int gn = bn + wn * 32 + nt * 16 + m16;
        float v = acc[mt][nt][r];
        u16 sh, sl;
        if (MODE == 0) {
          if (gm < M) {
            split2(v, sh, sl);
            size_t idx = (size_t)gm * Ntot + gn;
            O1h[idx] = sh; O1l[idx] = sl;
          }
        } else if (MODE == 1) {
          if (gn < TCD) {
            split2(v, sh, sl);
            size_t row = (size_t)(gm >> 11) * JTOT + 141 + (gm & 2047);
            O1h[row * TCD + gn] = sh; O1l[row * TCD + gn] = sl;
          } else {
            Oi1[(size_t)gm * INNER + (gn - TCD)] = pack_split(v * SCALE);
          }
        } else if (MODE == 2) {
          if (gm < M) {
            if (gn < INNER) Oi1[(size_t)gm * INNER + gn] = pack_split(v);
            else            Oi2[(size_t)gm * INNER + (gn - INNER)] = pack_split(v);
          }
        } else {
          Of[(size_t)gm * QD + gn] = v + bias[gn];
        }
      }
}

__global__ __launch_bounds__(256) void copy_ctx_kernel(
    const float* __restrict__ context, const u16* __restrict__ pch,
    const u16* __restrict__ pcl, u16* __restrict__ ch, u16* __restrict__ cl) {
  int idx = blockIdx.x * 256 + threadIdx.x;
  const int total = BB * 141 * TCD;
  if (idx >= total) return;
  int c = idx % TCD;
  int r = (idx / TCD) % 141;
  int b = idx / (141 * TCD);
  size_t dst = ((size_t)b * JTOT + r) * TCD + c;
  if (r < CTX_LEN) {
    u16 sh, sl;
    split2(context[((size_t)b * CTX_LEN + r) * TCD + c], sh, sl);
    ch[dst] = sh; cl[dst] = sl;
  } else {
    size_t s = (size_t)(r - CTX_LEN) * TCD + c;
    ch[dst] = pch[s]; cl[dst] = pcl[s];
  }
}

// ---------------- MFMA flash attention (R4 structure, interleaved u32 q/k/v) ----------------
// Block: 64 q-rows of one (b,h). 4 waves x 16 rows. J-tiles of 64, 3 barriers/tile.
// LDS: Kp[64*68] + Vt[64*66] + Pp[64*68] u32 = 51712 B. Staging = pure copies.
__global__ __launch_bounds__(256) void attn_mfma(
    const u32* __restrict__ qg, const u32* __restrict__ kg,
    const u32* __restrict__ vg, u16* __restrict__ aoh, u16* __restrict__ aol) {
  __shared__ __align__(16) u32 Kp[64 * 68];
  __shared__ __align__(16) u32 Vt[64 * 66];
  __shared__ __align__(16) u32 Pp[64 * 68];

  const int t = threadIdx.x;
  const int w = t >> 6;
  const int lane = t & 63;
  const int m16 = lane & 15;
  const int quad = lane >> 4;

  const int blk = blockIdx.x;
  const int qt = blk & 31;
  const int bh = blk >> 5;
  const int b = bh >> 3, h = bh & 7;
  const int qrow0 = qt * 64;

  const u32* qb = qg + ((size_t)(b * NN + qrow0)) * INNER + h * 64;
  const u32* kb = kg + (size_t)b * JTOT * INNER + h * 64;
  const u32* vb = vg + (size_t)b * JTOT * INNER + h * 64;

  // ---- stage Q (interleaved copy; pre-scaled by producer) ----
#pragma unroll
  for (int i = 0; i < 4; ++i) {
    int idx4 = t + i * 256;
    int r = idx4 >> 4;
    int dc = (idx4 & 15) * 4;
    *(uint4*)&Pp[r * 68 + dc] = *(const uint4*)(qb + (size_t)r * INNER + dc);
  }
  __syncthreads();

  bf16x8 qh[2], ql[2];
#pragma unroll
  for (int ks = 0; ks < 2; ++ks) {
    const u32* p = &Pp[(w * 16 + m16) * 68 + ks * 32 + quad * 8];
    uint4 a = *(const uint4*)p, bq = *(const uint4*)(p + 4);
    u32 u[8] = {a.x, a.y, a.z, a.w, bq.x, bq.y, bq.z, bq.w};
    unpack8(u, qh[ks], ql[ks]);
  }

  f32x4 O[4] = {{0.f,0.f,0.f,0.f},{0.f,0.f,0.f,0.f},{0.f,0.f,0.f,0.f},{0.f,0.f,0.f,0.f}};
  float mrow[4], lrow[4];
#pragma unroll
  for (int r = 0; r < 4; ++r) { mrow[r] = -INFINITY; lrow[r] = 0.f; }

  const uint4 Z = {0u, 0u, 0u, 0u};

  for (int j0 = 0; j0 < JTOT; j0 += 64) {
    __syncthreads();
    // ---- stage K (row copy) and V (transposed scatter) ----
#pragma unroll
    for (int i = 0; i < 4; ++i) {
      int idx4 = t + i * 256;
      int jr = idx4 >> 4;
      int dc = (idx4 & 15) * 4;
      int jg = j0 + jr;
      uint4 pk = Z, pv = Z;
      if (jg < JTOT) {
        pk = *(const uint4*)(kb + (size_t)jg * INNER + dc);
        pv = *(const uint4*)(vb + (size_t)jg * INNER + dc);
      }
      *(uint4*)&Kp[jr * 68 + dc] = pk;
      Vt[(dc + 0) * 66 + jr] = pv.x;
      Vt[(dc + 1) * 66 + jr] = pv.y;
      Vt[(dc + 2) * 66 + jr] = pv.z;
      Vt[(dc + 3) * 66 + jr] = pv.w;
    }
    __syncthreads();

    // ---- S = Q K^T ----
    f32x4 S[4];
#pragma unroll
    for (int jt = 0; jt < 4; ++jt) {
      f32x4 acc = {0.f, 0.f, 0.f, 0.f};
#pragma unroll
      for (int ks = 0; ks < 2; ++ks) {
        const u32* p = &Kp[(jt * 16 + m16) * 68 + ks * 32 + quad * 8];
        uint4 a = *(const uint4*)p, bq = *(const uint4*)(p + 4);
        u32 u[8] = {a.x, a.y, a.z, a.w, bq.x, bq.y, bq.z, bq.w};
        bf16x8 kh, kl;
        unpack8(u, kh, kl);
        acc = __builtin_amdgcn_mfma_f32_16x16x32_bf16(qh[ks], kh, acc, 0, 0, 0);
        acc = __builtin_amdgcn_mfma_f32_16x16x32_bf16(qh[ks], kl, acc, 0, 0, 0);
        acc = __builtin_amdgcn_mfma_f32_16x16x32_bf16(ql[ks], kh, acc, 0, 0, 0);
      }
      S[jt] = acc;
    }

#pragma unroll
    for (int jt = 0; jt < 4; ++jt) {
      int jc = j0 + jt * 16 + m16;
      if (jc >= JTOT) {
#pragma unroll
        for (int r = 0; r < 4; ++r) S[jt][r] = -INFINITY;
      }
    }

    // ---- online softmax ----
    float pj[4][4];
#pragma unroll
    for (int r = 0; r < 4; ++r) {
      float mx = fmaxf(fmaxf(S[0][r], S[1][r]), fmaxf(S[2][r], S[3][r]));
#pragma unroll
      for (int off = 1; off < 16; off <<= 1)
        mx = fmaxf(mx, __shfl_xor(mx, off, 64));
      float mnew = fmaxf(mrow[r], mx);
      float alpha = __expf(mrow[r] - mnew);
      mrow[r] = mnew;
      float rs = 0.f;
#pragma unroll
      for (int jt = 0; jt < 4; ++jt) {
        float p = __expf(S[jt][r] - mnew);
        pj[jt][r] = p;
        rs += p;
      }
#pragma unroll
      for (int off = 1; off < 16; off <<= 1)
        rs += __shfl_xor(rs, off, 64);
      lrow[r] = lrow[r] * alpha + rs;
#pragma unroll
      for (int nt = 0; nt < 4; ++nt) O[nt][r] *= alpha;
    }

    // ---- write P (interleaved, C-layout) ----
#pragma unroll
    for (int jt = 0; jt < 4; ++jt)
#pragma unroll
      for (int r = 0; r < 4; ++r)
        Pp[(w * 16 + quad * 4 + r) * 68 + jt * 16 + m16] = pack_split(pj[jt][r]);
    __syncthreads();

    // ---- O += P V ----
    bf16x8 ph[2], pl[2];
#pragma unroll
    for (int ks = 0; ks < 2; ++ks) {
      const u32* p = &Pp[(w * 16 + m16) * 68 + ks * 32 + quad * 8];
      uint4 a = *(const uint4*)p, bq = *(const uint4*)(p + 4);
      u32 u[8] = {a.x, a.y, a.z, a.w, bq.x, bq.y, bq.z, bq.w};
      unpack8(u, ph[ks], pl[ks]);
    }
#pragma unroll
    for (int nt = 0; nt < 4; ++nt) {
#pragma unroll
      for (int ks = 0; ks < 2; ++ks) {
        const u32* p = &Vt[(nt * 16 + m16) * 66 + ks * 32 + quad * 8];
        uint2 a = *(const uint2*)p,       b2 = *(const uint2*)(p + 2);
        uint2 c = *(const uint2*)(p + 4), d2 = *(const uint2*)(p + 6);
        u32 u[8] = {a.x, a.y, b2.x, b2.y, c.x, c.y, d2.x, d2.y};
        bf16x8 vh, vl;
        unpack8(u, vh, vl);
        O[nt] = __builtin_amdgcn_mfma_f32_16x16x32_bf16(ph[ks], vh, O[nt], 0, 0, 0);
        O[nt] = __builtin_amdgcn_mfma_f32_16x16x32_bf16(ph[ks], vl, O[nt], 0, 0, 0);
        O[nt] = __builtin_amdgcn_mfma_f32_16x16x32_bf16(pl[ks], vh, O[nt], 0, 0, 0);
      }
    }
  }

  // ---- epilogue: normalize + store ao planes ----
  float inv[4];
#pragma unroll
  for (int r = 0; r < 4; ++r) inv[r] = 1.f / lrow[r];
#pragma unroll
  for (int nt = 0; nt < 4; ++nt)
#pragma unroll
    for (int r = 0; r < 4; ++r) {
      size_t idx = ((size_t)(b * NN + qrow0 + w * 16 + quad * 4 + r)) * INNER +
                   h * 64 + nt * 16 + m16;
      u16 sh, sl;
      split2(O[nt][r] * inv[r], sh, sl);
      aoh[idx] = sh; aol[idx] = sl;
    }
}

// ---------------- launch ----------------
extern "C" void kernel_launch(void* const* d_in, const int* in_sizes, int n_in,
                              void* d_out, int out_size, void* d_ws, size_t ws_size,
                              hipStream_t stream) {
  const float* x        = (const float*)d_in[0];
  const float* context  = (const float*)d_in[1];
  const float* prompt   = (const float*)d_in[2];
  const float* w_prompt = (const float*)d_in[3];
  const float* w_img    = (const float*)d_in[4];
  const float* w_q      = (const float*)d_in[5];
  const float* w_k      = (const float*)d_in[6];
  const float* w_v      = (const float*)d_in[7];
  const float* w_out    = (const float*)d_in[8];
  const float* b_out    = (const float*)d_in[9];
  float* out = (float*)d_out;

  const int M = MTOT;             // 4096
  const int MJ = BB * JTOT;       // 4378

  u16* p = (u16*)d_ws;
  const size_t qN = (size_t)M * INNER, ctxN = (size_t)MJ * TCD, kvN = (size_t)MJ * INNER;
  u16* pch = p; p += (size_t)NUM_PROMPT * TCD;
  u16* pcl = p; p += (size_t)NUM_PROMPT * TCD;
  u16* cth = p; p += ctxN; u16* ctl = p; p += ctxN;
  u16* aoh = p; p += qN;   u16* aol = p; p += qN;
  u16* WtPh = p; p += (size_t)TCD * PD;            u16* WtPl = p; p += (size_t)TCD * PD;
  u16* WtAh = p; p += (size_t)(TCD + INNER) * QD;  u16* WtAl = p; p += (size_t)(TCD + INNER) * QD;
  u16* WtBh = p; p += (size_t)(2 * INNER) * TCD;   u16* WtBl = p; p += (size_t)(2 * INNER) * TCD;
  u16* WtOh = p; p += (size_t)QD * INNER;          u16* WtOl = p; p += (size_t)QD * INNER;
  u32* pi = (u32*)p;
  u32* qi = pi;                 pi += qN;    // interleaved q (pre-scaled)
  u32* ki = pi;                 pi += kvN;   // interleaved k
  u32* vi = pi;                 pi += kvN;   // interleaved v

  transpose_pack<<<dim3(TCD / 32, PD / 32), 256, 0, stream>>>(w_prompt, WtPh, WtPl, PD, TCD);
  transpose_pack<<<dim3(TCD / 32, QD / 32), 256, 0, stream>>>(w_img, WtAh, WtAl, QD, TCD);
  transpose_pack<<<dim3(INNER / 32, QD / 32), 256, 0, stream>>>(
      w_q, WtAh + (size_t)TCD * QD, WtAl + (size_t)TCD * QD, QD, INNER);
  transpose_pack<<<dim3(INNER / 32, TCD / 32), 256, 0, stream>>>(w_k, WtBh, WtBl, TCD, INNER);
  transpose_pack<<<dim3(INNER / 32, TCD / 32), 256, 0, stream>>>(
      w_v, WtBh + (size_t)INNER * TCD, WtBl + (size_t)INNER * TCD, TCD, INNER);
  transpose_pack<<<dim3(QD / 32, INNER / 32), 256, 0, stream>>>(w_out, WtOh, WtOl, INNER, QD);

  // prompt_ctx -> planes
  gemm_mfma<0, true><<<dim3(TCD / 64, 1), 256, 0, stream>>>(
      prompt, nullptr, nullptr, WtPh, WtPl, pch, pcl, nullptr, nullptr, nullptr, nullptr,
      NUM_PROMPT, PD, TCD);
  copy_ctx_kernel<<<(BB * 141 * TCD + 255) / 256, 256, 0, stream>>>(context, pch, pcl, cth, ctl);
  // x @ [w_img | w_q] -> ctx planes (remap) + q interleaved (x SCALE)
  gemm_mfma<1, true><<<dim3((TCD + INNER) / 64, M / 128), 256, 0, stream>>>(
      x, nullptr, nullptr, WtAh, WtAl, cth, ctl, qi, nullptr, nullptr, nullptr,
      M, QD, TCD + INNER);
  // ctx @ [w_k | w_v] -> k/v interleaved
  gemm_mfma<2, false><<<dim3((2 * INNER) / 64, (MJ + 127) / 128), 256, 0, stream>>>(
      nullptr, cth, ctl, WtBh, WtBl, nullptr, nullptr, ki, vi, nullptr, nullptr,
      MJ, TCD, 2 * INNER);
  // attention (R4 structure)
  attn_mfma<<<BB * HEADS * (NN / 64), 256, 0, stream>>>(qi, ki, vi, aoh, aol);
  // out = ao @ w_out + b_out
  gemm_mfma<3, false><<<dim3(QD / 64, M / 128), 256, 0, stream>>>(
      nullptr, aoh, aol, WtOh, WtOl, nullptr, nullptr, nullptr, nullptr, out, b_out,
      M, INNER, QD);
}

// Round 11
// 386.178 us; speedup vs baseline: 2.7572x; 1.0628x over previous
//
#include <hip/hip_runtime.h>
#include <hip/hip_bf16.h>
#include <math.h>

#define BB 2
#define NN 2048
#define QD 1024
#define CTX_LEN 77
#define TCD 768
#define NUM_PROMPT 64
#define PD 1024
#define HEADS 8
#define DIM_HEAD 64
#define INNER 512
#define JTOT (CTX_LEN + NUM_PROMPT + NN)   // 2189
#define SCALE 0.125f
#define MTOT (BB * NN)                     // 4096

typedef unsigned short u16;
typedef unsigned int u32;
typedef __attribute__((ext_vector_type(8))) short bf16x8;
typedef __attribute__((ext_vector_type(4))) float f32x4;

__device__ __forceinline__ u32 pack_split(float f) {   // interleaved: low16=hi, high16=lo
  u32 u = __builtin_bit_cast(u32, f);
  u32 hi = u & 0xffff0000u;
  float lo = f - __builtin_bit_cast(float, hi);
  u32 ul = __builtin_bit_cast(u32, lo);
  return __builtin_amdgcn_perm(ul, u, 0x07060302u);
}
__device__ __forceinline__ void split2(float f, u16& h, u16& l) {
  u32 u = __builtin_bit_cast(u32, f);
  u32 hm = u & 0xffff0000u;
  float lo = f - __builtin_bit_cast(float, hm);
  h = (u16)(u >> 16);
  l = (u16)(__builtin_bit_cast(u32, lo) >> 16);
}
__device__ __forceinline__ void unpack8(const u32* u, bf16x8& hf, bf16x8& lf) {
  union { u32 w[4]; bf16x8 v; } H, L;
#pragma unroll
  for (int i = 0; i < 4; ++i) {
    H.w[i] = __builtin_amdgcn_perm(u[2 * i + 1], u[2 * i], 0x05040100u);
    L.w[i] = __builtin_amdgcn_perm(u[2 * i + 1], u[2 * i], 0x07060302u);
  }
  hf = H.v; lf = L.v;
}

// async global->LDS, 16B per lane; lds dest = base + lane*16
__device__ __forceinline__ void gload16(const u16* g, u32* l) {
  __builtin_amdgcn_global_load_lds(
      (const __attribute__((address_space(1))) u32*)(const void*)g,
      (__attribute__((address_space(3))) u32*)(void*)l, 16, 0, 0);
}

// ---------------- f32 -> hi/lo plane pack (elementwise) ----------------
__global__ __launch_bounds__(256) void pack_planes(
    const float* __restrict__ src, u16* __restrict__ dh, u16* __restrict__ dl, int n4) {
  int i = blockIdx.x * 256 + threadIdx.x;
  if (i >= n4) return;
  float4 f = ((const float4*)src)[i];
  ushort4 hh, ll;
  split2(f.x, hh.x, ll.x); split2(f.y, hh.y, ll.y);
  split2(f.z, hh.z, ll.z); split2(f.w, hh.w, ll.w);
  ((ushort4*)dh)[i] = hh;
  ((ushort4*)dl)[i] = ll;
}

// ---------------- weight transpose+pack: src[K,N] f32 -> hi/lo[N,K] planes ----------------
__global__ __launch_bounds__(256) void transpose_pack(
    const float* __restrict__ src, u16* __restrict__ dh, u16* __restrict__ dl,
    int K, int N) {
  __shared__ u32 T[32][33];
  const int t = threadIdx.x;
  const int k0 = blockIdx.y * 32, n0 = blockIdx.x * 32;
#pragma unroll
  for (int i = 0; i < 4; ++i) {
    int e = t + i * 256;
    int kr = e >> 5, nc = e & 31;
    T[kr][nc] = pack_split(src[(size_t)(k0 + kr) * N + n0 + nc]);
  }
  __syncthreads();
#pragma unroll
  for (int i = 0; i < 4; ++i) {
    int e = t + i * 256;
    int nr = e >> 5, kc = e & 31;
    u32 w = T[kc][nr];
    size_t idx = (size_t)(n0 + nr) * K + k0 + kc;
    dh[idx] = (u16)(w & 0xffff);
    dl[idx] = (u16)(w >> 16);
  }
}

// ---------------- split-bf16 MFMA GEMM, 128x64 tiles, global_load_lds staging ----------------
// A, B both hi/lo bf16 planes, rows of K u16. LDS rows: 16 u32 (64B), unpadded (m97 geometry).
// MODE 0: plane output -> O1h/O1l
// MODE 1: gn<TCD -> ctx planes (row remap); else q interleaved u32 (x SCALE) -> Oi1
// MODE 2: gn<INNER -> k interleaved -> Oi1; else v interleaved -> Oi2
// MODE 3: f32 out + bias
template <int MODE>
__global__ __launch_bounds__(256) void gemm_mfma(
    const u16* __restrict__ Agh, const u16* __restrict__ Agl,
    const u16* __restrict__ Bgh, const u16* __restrict__ Bgl,
    u16* __restrict__ O1h, u16* __restrict__ O1l,
    u32* __restrict__ Oi1, u32* __restrict__ Oi2,
    float* __restrict__ Of, const float* __restrict__ bias,
    int M, int K, int Ntot) {
  __shared__ __align__(16) u32 Ah_s[128 * 16];
  __shared__ __align__(16) u32 Al_s[128 * 16];
  __shared__ __align__(16) u32 Bh_s[64 * 16];
  __shared__ __align__(16) u32 Bl_s[64 * 16];

  const int t = threadIdx.x;
  const int w = t >> 6, lane = t & 63;
  const int m16 = lane & 15, quad = lane >> 4;
  const int wm = w >> 1, wn = w & 1;
  const int bm = blockIdx.y * 128, bn = blockIdx.x * 64;

  // DMA staging geometry: 4 lanes per 64B row, lane's 16B slot = (lane&3)*8 u16.
  // Wave w: A rows 32w..32w+31 (2 calls of 16 rows), B rows 16w..16w+15 (1 call).
  const int acol = (lane & 3) * 8;
  const int ar0 = 32 * w + (lane >> 2);
  const int ar1 = ar0 + 16;
  const int ag0 = min(bm + ar0, M - 1);   // clamp: OOB rows read valid garbage,
  const int ag1 = min(bm + ar1, M - 1);   // results guarded out in epilogue
  const u16* a0h = Agh + (size_t)ag0 * K + acol;
  const u16* a1h = Agh + (size_t)ag1 * K + acol;
  const u16* a0l = Agl + (size_t)ag0 * K + acol;
  const u16* a1l = Agl + (size_t)ag1 * K + acol;
  const int br = 16 * w + (lane >> 2);
  const u16* b0h = Bgh + (size_t)(bn + br) * K + acol;
  const u16* b0l = Bgl + (size_t)(bn + br) * K + acol;

  u32* AhD0 = &Ah_s[(2 * w) * 256];
  u32* AhD1 = &Ah_s[(2 * w + 1) * 256];
  u32* AlD0 = &Al_s[(2 * w) * 256];
  u32* AlD1 = &Al_s[(2 * w + 1) * 256];
  u32* BhD = &Bh_s[w * 256];
  u32* BlD = &Bl_s[w * 256];

  f32x4 acc[4][2];
#pragma unroll
  for (int i = 0; i < 4; ++i)
#pragma unroll
    for (int j = 0; j < 2; ++j) acc[i][j] = (f32x4){0.f, 0.f, 0.f, 0.f};

  for (int k0 = 0; k0 < K; k0 += 32) {
    // ---- async stage (no VGPR round-trip) ----
    gload16(a0h + k0, AhD0);
    gload16(a1h + k0, AhD1);
    gload16(a0l + k0, AlD0);
    gload16(a1l + k0, AlD1);
    gload16(b0h + k0, BhD);
    gload16(b0l + k0, BlD);
    __syncthreads();   // drains DMA (compiler emits vmcnt(0) before barrier)

    bf16x8 ah[4], al[4], bh[2], bl[2];
#pragma unroll
    for (int mt = 0; mt < 4; ++mt) {
      int off = (wm * 64 + mt * 16 + m16) * 16 + quad * 4;
      ah[mt] = *(const bf16x8*)&Ah_s[off];
      al[mt] = *(const bf16x8*)&Al_s[off];
    }
#pragma unroll
    for (int nt = 0; nt < 2; ++nt) {
      int off = (wn * 32 + nt * 16 + m16) * 16 + quad * 4;
      bh[nt] = *(const bf16x8*)&Bh_s[off];
      bl[nt] = *(const bf16x8*)&Bl_s[off];
    }
#pragma unroll
    for (int mt = 0; mt < 4; ++mt)
#pragma unroll
      for (int nt = 0; nt < 2; ++nt) {
        acc[mt][nt] = __builtin_amdgcn_mfma_f32_16x16x32_bf16(ah[mt], bh[nt], acc[mt][nt], 0, 0, 0);
        acc[mt][nt] = __builtin_amdgcn_mfma_f32_16x16x32_bf16(ah[mt], bl[nt], acc[mt][nt], 0, 0, 0);
        acc[mt][nt] = __builtin_amdgcn_mfma_f32_16x16x32_bf16(al[mt], bh[nt], acc[mt][nt], 0, 0, 0);
      }
    __syncthreads();   // frag reads done before next DMA overwrites
  }

#pragma unroll
  for (int mt = 0; mt < 4; ++mt)
#pragma unroll
    for (int nt = 0; nt < 2; ++nt)
#pragma unroll
      for (int r = 0; r < 4; ++r) {
        int gm = bm + wm * 64 + mt * 16 + quad * 4 + r;
        int gn = bn + wn * 32 + nt * 16 + m16;
        float v = acc[mt][nt][r];
        u16 sh, sl;
        if (MODE == 0) {
          if (gm < M) {
            split2(v, sh, sl);
            size_t idx = (size_t)gm * Ntot + gn;
            O1h[idx] = sh; O1l[idx] = sl;
          }
        } else if (MODE == 1) {
          if (gn < TCD) {
            split2(v, sh, sl);
            size_t row = (size_t)(gm >> 11) * JTOT + 141 + (gm & 2047);
            O1h[row * TCD + gn] = sh; O1l[row * TCD + gn] = sl;
          } else {
            Oi1[(size_t)gm * INNER + (gn - TCD)] = pack_split(v * SCALE);
          }
        } else if (MODE == 2) {
          if (gm < M) {
            if (gn < INNER) Oi1[(size_t)gm * INNER + gn] = pack_split(v);
            else            Oi2[(size_t)gm * INNER + (gn - INNER)] = pack_split(v);
          }
        } else {
          Of[(size_t)gm * QD + gn] = v + bias[gn];
        }
      }
}

__global__ __launch_bounds__(256) void copy_ctx_kernel(
    const float* __restrict__ context, const u16* __restrict__ pch,
    const u16* __restrict__ pcl, u16* __restrict__ ch, u16* __restrict__ cl) {
  int idx = blockIdx.x * 256 + threadIdx.x;
  const int total = BB * 141 * TCD;
  if (idx >= total) return;
  int c = idx % TCD;
  int r = (idx / TCD) % 141;
  int b = idx / (141 * TCD);
  size_t dst = ((size_t)b * JTOT + r) * TCD + c;
  if (r < CTX_LEN) {
    u16 sh, sl;
    split2(context[((size_t)b * CTX_LEN + r) * TCD + c], sh, sl);
    ch[dst] = sh; cl[dst] = sl;
  } else {
    size_t s = (size_t)(r - CTX_LEN) * TCD + c;
    ch[dst] = pch[s]; cl[dst] = pcl[s];
  }
}

// ---------------- MFMA flash attention (R10 measured-best, unchanged) ----------------
__global__ __launch_bounds__(256) void attn_mfma(
    const u32* __restrict__ qg, const u32* __restrict__ kg,
    const u32* __restrict__ vg, u16* __restrict__ aoh, u16* __restrict__ aol) {
  __shared__ __align__(16) u32 Kp[64 * 68];
  __shared__ __align__(16) u32 Vt[64 * 66];
  __shared__ __align__(16) u32 Pp[64 * 68];

  const int t = threadIdx.x;
  const int w = t >> 6;
  const int lane = t & 63;
  const int m16 = lane & 15;
  const int quad = lane >> 4;

  const int blk = blockIdx.x;
  const int qt = blk & 31;
  const int bh = blk >> 5;
  const int b = bh >> 3, h = bh & 7;
  const int qrow0 = qt * 64;

  const u32* qb = qg + ((size_t)(b * NN + qrow0)) * INNER + h * 64;
  const u32* kb = kg + (size_t)b * JTOT * INNER + h * 64;
  const u32* vb = vg + (size_t)b * JTOT * INNER + h * 64;

#pragma unroll
  for (int i = 0; i < 4; ++i) {
    int idx4 = t + i * 256;
    int r = idx4 >> 4;
    int dc = (idx4 & 15) * 4;
    *(uint4*)&Pp[r * 68 + dc] = *(const uint4*)(qb + (size_t)r * INNER + dc);
  }
  __syncthreads();

  bf16x8 qh[2], ql[2];
#pragma unroll
  for (int ks = 0; ks < 2; ++ks) {
    const u32* p = &Pp[(w * 16 + m16) * 68 + ks * 32 + quad * 8];
    uint4 a = *(const uint4*)p, bq = *(const uint4*)(p + 4);
    u32 u[8] = {a.x, a.y, a.z, a.w, bq.x, bq.y, bq.z, bq.w};
    unpack8(u, qh[ks], ql[ks]);
  }

  f32x4 O[4] = {{0.f,0.f,0.f,0.f},{0.f,0.f,0.f,0.f},{0.f,0.f,0.f,0.f},{0.f,0.f,0.f,0.f}};
  float mrow[4], lrow[4];
#pragma unroll
  for (int r = 0; r < 4; ++r) { mrow[r] = -INFINITY; lrow[r] = 0.f; }

  const uint4 Z = {0u, 0u, 0u, 0u};

  for (int j0 = 0; j0 < JTOT; j0 += 64) {
    __syncthreads();
#pragma unroll
    for (int i = 0; i < 4; ++i) {
      int idx4 = t + i * 256;
      int jr = idx4 >> 4;
      int dc = (idx4 & 15) * 4;
      int jg = j0 + jr;
      uint4 pk = Z, pv = Z;
      if (jg < JTOT) {
        pk = *(const uint4*)(kb + (size_t)jg * INNER + dc);
        pv = *(const uint4*)(vb + (size_t)jg * INNER + dc);
      }
      *(uint4*)&Kp[jr * 68 + dc] = pk;
      Vt[(dc + 0) * 66 + jr] = pv.x;
      Vt[(dc + 1) * 66 + jr] = pv.y;
      Vt[(dc + 2) * 66 + jr] = pv.z;
      Vt[(dc + 3) * 66 + jr] = pv.w;
    }
    __syncthreads();

    f32x4 S[4];
#pragma unroll
    for (int jt = 0; jt < 4; ++jt) {
      f32x4 acc = {0.f, 0.f, 0.f, 0.f};
#pragma unroll
      for (int ks = 0; ks < 2; ++ks) {
        const u32* p = &Kp[(jt * 16 + m16) * 68 + ks * 32 + quad * 8];
        uint4 a = *(const uint4*)p, bq = *(const uint4*)(p + 4);
        u32 u[8] = {a.x, a.y, a.z, a.w, bq.x, bq.y, bq.z, bq.w};
        bf16x8 kh, kl;
        unpack8(u, kh, kl);
        acc = __builtin_amdgcn_mfma_f32_16x16x32_bf16(qh[ks], kh, acc, 0, 0, 0);
        acc = __builtin_amdgcn_mfma_f32_16x16x32_bf16(qh[ks], kl, acc, 0, 0, 0);
        acc = __builtin_amdgcn_mfma_f32_16x16x32_bf16(ql[ks], kh, acc, 0, 0, 0);
      }
      S[jt] = acc;
    }

#pragma unroll
    for (int jt = 0; jt < 4; ++jt) {
      int jc = j0 + jt * 16 + m16;
      if (jc >= JTOT) {
#pragma unroll
        for (int r = 0; r < 4; ++r) S[jt][r] = -INFINITY;
      }
    }

    float pj[4][4];
#pragma unroll
    for (int r = 0; r < 4; ++r) {
      float mx = fmaxf(fmaxf(S[0][r], S[1][r]), fmaxf(S[2][r], S[3][r]));
#pragma unroll
      for (int off = 1; off < 16; off <<= 1)
        mx = fmaxf(mx, __shfl_xor(mx, off, 64));
      float mnew = fmaxf(mrow[r], mx);
      float alpha = __expf(mrow[r] - mnew);
      mrow[r] = mnew;
      float rs = 0.f;
#pragma unroll
      for (int jt = 0; jt < 4; ++jt) {
        float p = __expf(S[jt][r] - mnew);
        pj[jt][r] = p;
        rs += p;
      }
#pragma unroll
      for (int off = 1; off < 16; off <<= 1)
        rs += __shfl_xor(rs, off, 64);
      lrow[r] = lrow[r] * alpha + rs;
#pragma unroll
      for (int nt = 0; nt < 4; ++nt) O[nt][r] *= alpha;
    }

#pragma unroll
    for (int jt = 0; jt < 4; ++jt)
#pragma unroll
      for (int r = 0; r < 4; ++r)
        Pp[(w * 16 + quad * 4 + r) * 68 + jt * 16 + m16] = pack_split(pj[jt][r]);
    __syncthreads();

    bf16x8 ph[2], pl[2];
#pragma unroll
    for (int ks = 0; ks < 2; ++ks) {
      const u32* p = &Pp[(w * 16 + m16) * 68 + ks * 32 + quad * 8];
      uint4 a = *(const uint4*)p, bq = *(const uint4*)(p + 4);
      u32 u[8] = {a.x, a.y, a.z, a.w, bq.x, bq.y, bq.z, bq.w};
      unpack8(u, ph[ks], pl[ks]);
    }
#pragma unroll
    for (int nt = 0; nt < 4; ++nt) {
#pragma unroll
      for (int ks = 0; ks < 2; ++ks) {
        const u32* p = &Vt[(nt * 16 + m16) * 66 + ks * 32 + quad * 8];
        uint2 a = *(const uint2*)p,       b2 = *(const uint2*)(p + 2);
        uint2 c = *(const uint2*)(p + 4), d2 = *(const uint2*)(p + 6);
        u32 u[8] = {a.x, a.y, b2.x, b2.y, c.x, c.y, d2.x, d2.y};
        bf16x8 vh, vl;
        unpack8(u, vh, vl);
        O[nt] = __builtin_amdgcn_mfma_f32_16x16x32_bf16(ph[ks], vh, O[nt], 0, 0, 0);
        O[nt] = __builtin_amdgcn_mfma_f32_16x16x32_bf16(ph[ks], vl, O[nt], 0, 0, 0);
        O[nt] = __builtin_amdgcn_mfma_f32_16x16x32_bf16(pl[ks], vh, O[nt], 0, 0, 0);
      }
    }
  }

  float inv[4];
#pragma unroll
  for (int r = 0; r < 4; ++r) inv[r] = 1.f / lrow[r];
#pragma unroll
  for (int nt = 0; nt < 4; ++nt)
#pragma unroll
    for (int r = 0; r < 4; ++r) {
      size_t idx = ((size_t)(b * NN + qrow0 + w * 16 + quad * 4 + r)) * INNER +
                   h * 64 + nt * 16 + m16;
      u16 sh, sl;
      split2(O[nt][r] * inv[r], sh, sl);
      aoh[idx] = sh; aol[idx] = sl;
    }
}

// ---------------- launch ----------------
extern "C" void kernel_launch(void* const* d_in, const int* in_sizes, int n_in,
                              void* d_out, int out_size, void* d_ws, size_t ws_size,
                              hipStream_t stream) {
  const float* x        = (const float*)d_in[0];
  const float* context  = (const float*)d_in[1];
  const float* prompt   = (const float*)d_in[2];
  const float* w_prompt = (const float*)d_in[3];
  const float* w_img    = (const float*)d_in[4];
  const float* w_q      = (const float*)d_in[5];
  const float* w_k      = (const float*)d_in[6];
  const float* w_v      = (const float*)d_in[7];
  const float* w_out    = (const float*)d_in[8];
  const float* b_out    = (const float*)d_in[9];
  float* out = (float*)d_out;

  const int M = MTOT;             // 4096
  const int MJ = BB * JTOT;       // 4378

  u16* p = (u16*)d_ws;
  const size_t qN = (size_t)M * INNER, ctxN = (size_t)MJ * TCD, kvN = (size_t)MJ * INNER;
  u16* pch = p; p += (size_t)NUM_PROMPT * TCD;
  u16* pcl = p; p += (size_t)NUM_PROMPT * TCD;
  u16* cth = p; p += ctxN; u16* ctl = p; p += ctxN;
  u16* aoh = p; p += qN;   u16* aol = p; p += qN;
  u16* xh  = p; p += (size_t)M * QD;   u16* xl  = p; p += (size_t)M * QD;
  u16* prh = p; p += (size_t)NUM_PROMPT * PD;
  u16* prl = p; p += (size_t)NUM_PROMPT * PD;
  u16* WtPh = p; p += (size_t)TCD * PD;            u16* WtPl = p; p += (size_t)TCD * PD;
  u16* WtAh = p; p += (size_t)(TCD + INNER) * QD;  u16* WtAl = p; p += (size_t)(TCD + INNER) * QD;
  u16* WtBh = p; p += (size_t)(2 * INNER) * TCD;   u16* WtBl = p; p += (size_t)(2 * INNER) * TCD;
  u16* WtOh = p; p += (size_t)QD * INNER;          u16* WtOl = p; p += (size_t)QD * INNER;
  u32* pi = (u32*)p;
  u32* qi = pi;                 pi += qN;    // interleaved q (pre-scaled)
  u32* ki = pi;                 pi += kvN;   // interleaved k
  u32* vi = pi;                 pi += kvN;   // interleaved v

  // ---- pack inputs + weights ----
  pack_planes<<<(M * QD / 4 + 255) / 256, 256, 0, stream>>>(x, xh, xl, M * QD / 4);
  pack_planes<<<(NUM_PROMPT * PD / 4 + 255) / 256, 256, 0, stream>>>(
      prompt, prh, prl, NUM_PROMPT * PD / 4);
  transpose_pack<<<dim3(TCD / 32, PD / 32), 256, 0, stream>>>(w_prompt, WtPh, WtPl, PD, TCD);
  transpose_pack<<<dim3(TCD / 32, QD / 32), 256, 0, stream>>>(w_img, WtAh, WtAl, QD, TCD);
  transpose_pack<<<dim3(INNER / 32, QD / 32), 256, 0, stream>>>(
      w_q, WtAh + (size_t)TCD * QD, WtAl + (size_t)TCD * QD, QD, INNER);
  transpose_pack<<<dim3(INNER / 32, TCD / 32), 256, 0, stream>>>(w_k, WtBh, WtBl, TCD, INNER);
  transpose_pack<<<dim3(INNER / 32, TCD / 32), 256, 0, stream>>>(
      w_v, WtBh + (size_t)INNER * TCD, WtBl + (size_t)INNER * TCD, TCD, INNER);
  transpose_pack<<<dim3(QD / 32, INNER / 32), 256, 0, stream>>>(w_out, WtOh, WtOl, INNER, QD);

  // ---- prompt_ctx -> planes ----
  gemm_mfma<0><<<dim3(TCD / 64, 1), 256, 0, stream>>>(
      prh, prl, WtPh, WtPl, pch, pcl, nullptr, nullptr, nullptr, nullptr,
      NUM_PROMPT, PD, TCD);
  copy_ctx_kernel<<<(BB * 141 * TCD + 255) / 256, 256, 0, stream>>>(context, pch, pcl, cth, ctl);
  // ---- x @ [w_img | w_q] -> ctx planes (remap) + q interleaved (x SCALE) ----
  gemm_mfma<1><<<dim3((TCD + INNER) / 64, M / 128), 256, 0, stream>>>(
      xh, xl, WtAh, WtAl, cth, ctl, qi, nullptr, nullptr, nullptr,
      M, QD, TCD + INNER);
  // ---- ctx @ [w_k | w_v] -> k/v interleaved ----
  gemm_mfma<2><<<dim3((2 * INNER) / 64, (MJ + 127) / 128), 256, 0, stream>>>(
      cth, ctl, WtBh, WtBl, nullptr, nullptr, ki, vi, nullptr, nullptr,
      MJ, TCD, 2 * INNER);
  // ---- attention (R10 structure, unchanged) ----
  attn_mfma<<<BB * HEADS * (NN / 64), 256, 0, stream>>>(qi, ki, vi, aoh, aol);
  // ---- out = ao @ w_out + b_out ----
  gemm_mfma<3><<<dim3(QD / 64, M / 128), 256, 0, stream>>>(
      aoh, aol, WtOh, WtOl, nullptr, nullptr, nullptr, nullptr, out, b_out,
      M, INNER, QD);
}